// Round 6
// baseline (130.398 us; speedup 1.0000x reference)
//
#include <hip/hip_runtime.h>
#include <math.h>

// QASA layer: out = circuit(x @ W_in.T + b_in, q_weights) @ W_out.T + b_out
// 8 qubits -> 256 complex amps. One row per wave (8192 waves).
// State idx = lane*4 + r: idx bits [7:2] = lane bits [5:0], [1:0] = reg.
// Wire i acts on idx bit 7-i: wires 0..5 -> lane bits 5..0, wires 6,7 -> regs.
// ALL cross-lane ops on the VALU pipe:
//   masks 1,2,8 -> DPP (quad_perm / row_ror:8)
//   mask 4      -> row_ror:4 (bit2==1) / row_ror:12 (bit2==0) + cndmask
//                  [row_ror:N = lane i reads lane (i-N) mod 16]
//   masks 16,32 -> v_permlane16/32_swap_b32: with equal inputs the two outputs
//                  are {self-half dup, other-half dup}; r0+r1-v = partner,
//                  independent of the swap direction.
// Zero LDS, zero DS-pipe traffic (fallback to ds_swizzle if builtins absent).

__device__ __forceinline__ int f2i(float v) { return __float_as_int(v); }
__device__ __forceinline__ float i2f(int v) { return __int_as_float(v); }

// plain DPP move (all lanes written)
template <int CTRL>
__device__ __forceinline__ float dppf(float v) {
    return i2f(__builtin_amdgcn_update_dpp(0, f2i(v), CTRL, 0xF, 0xF, true));
}
// masked DPP: lanes outside ROW/BANK masks keep `old` (write-gating only)
template <int CTRL, int ROW, int BANK>
__device__ __forceinline__ float dppm(float old_, float src) {
    return i2f(__builtin_amdgcn_update_dpp(f2i(old_), f2i(src), CTRL, ROW, BANK, false));
}

#if __has_builtin(__builtin_amdgcn_permlane32_swap) && __has_builtin(__builtin_amdgcn_permlane16_swap)
#define HAVE_PLSWAP 1
#endif

// partner<M>(v): value of v in lane (lane ^ M), via VALU only where possible
template <int MASK>
__device__ __forceinline__ float partner(float v, int lane) {
    if constexpr (MASK == 1)      return dppf<0xB1>(v);    // quad_perm [1,0,3,2]
    else if constexpr (MASK == 2) return dppf<0x4E>(v);    // quad_perm [2,3,0,1]
    else if constexpr (MASK == 8) return dppf<0x128>(v);   // row_ror:8 (self-inverse)
    else if constexpr (MASK == 4) {
        float a = dppf<0x124>(v);   // row_ror:4  -> i reads i-4 : right when bit2==1
        float b = dppf<0x12C>(v);   // row_ror:12 -> i reads i+4 : right when bit2==0
        return (lane & 4) ? a : b;
    }
#ifdef HAVE_PLSWAP
    else if constexpr (MASK == 16) {
        auto r = __builtin_amdgcn_permlane16_swap(f2i(v), f2i(v), false, false);
        return (i2f(r[0]) + i2f(r[1])) - v;   // {self, partner} -> partner
    } else {
        auto r = __builtin_amdgcn_permlane32_swap(f2i(v), f2i(v), false, false);
        return (i2f(r[0]) + i2f(r[1])) - v;   // {self, partner} -> partner
    }
#else
    else if constexpr (MASK == 16)
        return i2f(__builtin_amdgcn_ds_swizzle(f2i(v), 0x401F));
    else
        return __shfl_xor(v, 32, 64);
#endif
}

template <int L>
__device__ __forceinline__ float rdlane(float v) {
    return i2f(__builtin_amdgcn_readlane(f2i(v), L));
}

// RX(th1) then RZ(th2) on wire W (c=cos(th/2), s=sin(th/2))
template <int W>
__device__ __forceinline__ void rot_gate(float re[4], float im[4],
                                         float c1, float s1, float c2, float s2,
                                         int lane) {
    if constexpr (W <= 5) {
        constexpr int MASK = 1 << (5 - W);
#pragma unroll
        for (int r = 0; r < 4; ++r) {
            float pre = partner<MASK>(re[r], lane);
            float pim = partner<MASK>(im[r], lane);
            re[r] = c1 * re[r] + s1 * pim;
            im[r] = c1 * im[r] - s1 * pre;
        }
        float ss = (lane & MASK) ? s2 : -s2;
#pragma unroll
        for (int r = 0; r < 4; ++r) {
            float nr = c2 * re[r] - ss * im[r];
            im[r] = c2 * im[r] + ss * re[r];
            re[r] = nr;
        }
    } else {
        constexpr int P = (W == 6) ? 2 : 1;
        float nre[4], nim[4];
#pragma unroll
        for (int r = 0; r < 4; ++r) {
            nre[r] = c1 * re[r] + s1 * im[r ^ P];
            nim[r] = c1 * im[r] - s1 * re[r ^ P];
        }
#pragma unroll
        for (int r = 0; r < 4; ++r) {
            float ss = ((W == 6) ? ((r >> 1) & 1) : (r & 1)) ? s2 : -s2;
            re[r] = c2 * nre[r] - ss * nim[r];
            im[r] = c2 * nim[r] + ss * nre[r];
        }
    }
}

// ---- CNOTs (control wire i -> target wire i+1), VALU/DPP only ----
// ctrl lane bit5, tgt mask16
__device__ __forceinline__ void cnot_01(float re[4], float im[4], int lane) {
    const bool c = lane & 32;
#pragma unroll
    for (int r = 0; r < 4; ++r) {
        float p = partner<16>(re[r], lane); re[r] = c ? p : re[r];
        float q = partner<16>(im[r], lane); im[r] = c ? q : im[r];
    }
}
// ctrl lane bit4 (rows 1,3), tgt mask8: masked row_ror:8
__device__ __forceinline__ void cnot_12(float re[4], float im[4]) {
#pragma unroll
    for (int r = 0; r < 4; ++r) {
        re[r] = dppm<0x128, 0xA, 0xF>(re[r], re[r]);
        im[r] = dppm<0x128, 0xA, 0xF>(im[r], im[r]);
    }
}
// ctrl lane bit3 (banks 2,3), tgt mask4:
//   lanes 8-11 (bank2, bit2==0) need i+4 -> ror:12; lanes 12-15 (bank3) -> ror:4
__device__ __forceinline__ void cnot_23(float re[4], float im[4]) {
#pragma unroll
    for (int r = 0; r < 4; ++r) {
        float t = dppm<0x12C, 0xF, 0x4>(re[r], re[r]);
        re[r] = dppm<0x124, 0xF, 0x8>(t, re[r]);
        t = dppm<0x12C, 0xF, 0x4>(im[r], im[r]);
        im[r] = dppm<0x124, 0xF, 0x8>(t, im[r]);
    }
}
// ctrl lane bit2 (banks 1,3), tgt mask2: masked quad_perm [2,3,0,1]
__device__ __forceinline__ void cnot_34(float re[4], float im[4]) {
#pragma unroll
    for (int r = 0; r < 4; ++r) {
        re[r] = dppm<0x4E, 0xF, 0xA>(re[r], re[r]);
        im[r] = dppm<0x4E, 0xF, 0xA>(im[r], im[r]);
    }
}
// ctrl lane bit1, tgt mask1: quad_perm [0,1,3,2] (identity on lanes 0,1)
__device__ __forceinline__ void cnot_45(float re[4], float im[4]) {
#pragma unroll
    for (int r = 0; r < 4; ++r) {
        re[r] = dppf<0xB4>(re[r]);
        im[r] = dppf<0xB4>(im[r]);
    }
}
// ctrl lane bit0, tgt reg bit1: swap reg pairs (0,2),(1,3) where ctrl
__device__ __forceinline__ void cnot_56(float re[4], float im[4], int lane) {
    const bool c = lane & 1;
#pragma unroll
    for (int r = 0; r < 2; ++r) {
        float a = re[r], b = re[r + 2];
        re[r] = c ? b : a; re[r + 2] = c ? a : b;
        float ai = im[r], bi = im[r + 2];
        im[r] = c ? bi : ai; im[r + 2] = c ? ai : bi;
    }
}
// ctrl reg bit1, tgt reg bit0: swap regs 2,3 (free rename)
__device__ __forceinline__ void cnot_67(float re[4], float im[4]) {
    float t = re[2]; re[2] = re[3]; re[3] = t;
    t = im[2]; im[2] = im[3]; im[3] = t;
}

__global__ void __launch_bounds__(256, 8) qasa_kernel(
    const float* __restrict__ x, const float* __restrict__ W_in,
    const float* __restrict__ b_in, const float* __restrict__ qw,
    const float* __restrict__ W_out, const float* __restrict__ b_out,
    float* __restrict__ out)
{
    const int tid = threadIdx.x;
    const int lane = tid & 63;
    const size_t row = (size_t)blockIdx.x * 4 + (tid >> 6);

    // per-wave layer trig, lane-indexed (qw has exactly 64 entries)
    float vc, vs;
    __sincosf(0.5f * qw[lane], &vs, &vc);

    // ---- phase 1: angles = x[row] @ W_in.T + b_in ----
    float acc[8] = {0.f, 0.f, 0.f, 0.f, 0.f, 0.f, 0.f, 0.f};
    {
        const float4* xr = (const float4*)(x + row * 1024);
        const float4* w4 = (const float4*)W_in;
#pragma unroll
        for (int k = 0; k < 4; ++k) {
            float4 xv = xr[lane + 64 * k];
#pragma unroll
            for (int q = 0; q < 8; ++q) {
                float4 wv = w4[q * 256 + lane + 64 * k];
                acc[q] += xv.x * wv.x + xv.y * wv.y + xv.z * wv.z + xv.w * wv.w;
            }
        }
    }
    // partial-reduce each acc over lane bits {0,1,3} (DPP only)
#pragma unroll
    for (int q = 0; q < 8; ++q) {
        acc[q] += dppf<0xB1>(acc[q]);
        acc[q] += dppf<0x4E>(acc[q]);
        acc[q] += dppf<0x128>(acc[q]);
    }
    // transpose: lane picks acc[j], j = b0 | b1<<1 | b3<<2
    const int b0 = lane & 1, b1 = (lane >> 1) & 1, b3 = (lane >> 3) & 1;
    float t01 = b0 ? acc[1] : acc[0];
    float t23 = b0 ? acc[3] : acc[2];
    float t45 = b0 ? acc[5] : acc[4];
    float t67 = b0 ? acc[7] : acc[6];
    float ta = b1 ? t23 : t01;
    float tb = b1 ? t67 : t45;
    float A = b3 ? tb : ta;
    // finish: sum over lane bits {2,4,5}
    A += partner<4>(A, lane);
    A += partner<16>(A, lane);
    A += partner<32>(A, lane);
    A += b_in[b0 | (b1 << 1) | (b3 << 2)];
    float ec, es;
    __sincosf(0.5f * A, &es, &ec);  // lane L_q holds trig of angle q

    // ---- phase 2: circuit ----
    float re[4], im[4];
#pragma unroll
    for (int r = 0; r < 4; ++r) { re[r] = 0.f; im[r] = 0.f; }
    re[0] = (lane == 0) ? 1.f : 0.f;

    // embedding: RX(ang[q]);RZ(ang[q]) on wire q, trig in lane
    // L_q = (q&1) | ((q>>1)&1)<<1 | ((q>>2)&1)<<3
#define EMB(W_) { constexpr int L_ = ((W_) & 1) | ((((W_) >> 1) & 1) << 1) | ((((W_) >> 2) & 1) << 3); \
                  float c_ = rdlane<L_>(ec), s_ = rdlane<L_>(es); \
                  rot_gate<W_>(re, im, c_, s_, c_, s_, lane); }
    EMB(0) EMB(1) EMB(2) EMB(3) EMB(4) EMB(5) EMB(6) EMB(7)
#undef EMB

    // layers: qw[l][0][i] -> lane 16l+i (RX), qw[l][1][i] -> lane 16l+8+i (RZ)
#define LGATE(Lx, I_) rot_gate<I_>(re, im, \
        rdlane<16 * (Lx) + (I_)>(vc), rdlane<16 * (Lx) + (I_)>(vs), \
        rdlane<16 * (Lx) + 8 + (I_)>(vc), rdlane<16 * (Lx) + 8 + (I_)>(vs), lane);
#define LAYER(Lx) \
    LGATE(Lx, 0) LGATE(Lx, 1) LGATE(Lx, 2) LGATE(Lx, 3) \
    LGATE(Lx, 4) LGATE(Lx, 5) LGATE(Lx, 6) LGATE(Lx, 7) \
    cnot_01(re, im, lane); cnot_12(re, im); cnot_23(re, im); \
    cnot_34(re, im); cnot_45(re, im); cnot_56(re, im, lane); cnot_67(re, im);
    LAYER(0) LAYER(1) LAYER(2) LAYER(3)
#undef LAYER
#undef LGATE

    // ---- phase 3: expvals ----
    float p0 = re[0] * re[0] + im[0] * im[0];
    float p1 = re[1] * re[1] + im[1] * im[1];
    float p2 = re[2] * re[2] + im[2] * im[2];
    float p3 = re[3] * re[3] + im[3] * im[3];
    float psum = (p0 + p1) + (p2 + p3);
    float s6 = (p0 + p1) - (p2 + p3);   // wire6: reg bit1
    float s7 = (p0 + p2) - (p1 + p3);   // wire7: reg bit0

    // Walsh-Hadamard butterfly on psum: lane 2^b ends with <Z> for lane-bit b
    float v = psum;
    { float u = dppf<0xB1>(v);        v = (lane & 1)  ? (u - v) : (v + u); }
    { float u = dppf<0x4E>(v);        v = (lane & 2)  ? (u - v) : (v + u); }
    { float u = dppf<0x128>(v);       v = (lane & 8)  ? (u - v) : (v + u); }
    { float u = partner<4>(v, lane);  v = (lane & 4)  ? (u - v) : (v + u); }
    { float u = partner<16>(v, lane); v = (lane & 16) ? (u - v) : (v + u); }
    { float u = partner<32>(v, lane); v = (lane & 32) ? (u - v) : (v + u); }
    const float EV0 = rdlane<32>(v), EV1 = rdlane<16>(v), EV2 = rdlane<8>(v);
    const float EV3 = rdlane<4>(v),  EV4 = rdlane<2>(v),  EV5 = rdlane<1>(v);

    // s6/s7: partial DPP sums, interleave by bit0, finish with shared butterfly
    s6 += dppf<0xB1>(s6); s6 += dppf<0x4E>(s6); s6 += dppf<0x128>(s6);
    s7 += dppf<0xB1>(s7); s7 += dppf<0x4E>(s7); s7 += dppf<0x128>(s7);
    float w = (lane & 1) ? s7 : s6;
    w += partner<4>(w, lane);
    w += partner<16>(w, lane);
    w += partner<32>(w, lane);
    const float EV6 = rdlane<0>(w), EV7 = rdlane<1>(w);

    // ---- phase 4: out[row] = ev @ W_out.T + b_out (float4 per lane) ----
    const float4* wo = (const float4*)W_out;
    const float4* bo = (const float4*)b_out;
    float4* orow = (float4*)(out + row * 1024);
#pragma unroll
    for (int jj = 0; jj < 4; ++jj) {
        const int c4 = lane + 64 * jj;      // float4-col index; col0 = 4*c4
        float4 bias = bo[c4];
        float res[4];
#pragma unroll
        for (int c = 0; c < 4; ++c) {
            float4 wa = wo[2 * (4 * c4 + c)];
            float4 wb = wo[2 * (4 * c4 + c) + 1];
            res[c] = wa.x * EV0 + wa.y * EV1 + wa.z * EV2 + wa.w * EV3
                   + wb.x * EV4 + wb.y * EV5 + wb.z * EV6 + wb.w * EV7;
        }
        float4 o;
        o.x = bias.x + res[0]; o.y = bias.y + res[1];
        o.z = bias.z + res[2]; o.w = bias.w + res[3];
        orow[c4] = o;
    }
}

extern "C" void kernel_launch(void* const* d_in, const int* in_sizes, int n_in,
                              void* d_out, int out_size, void* d_ws, size_t ws_size,
                              hipStream_t stream) {
    const float* x     = (const float*)d_in[0];
    const float* W_in  = (const float*)d_in[1];
    const float* b_in  = (const float*)d_in[2];
    const float* qw    = (const float*)d_in[3];
    const float* W_out = (const float*)d_in[4];
    const float* b_out = (const float*)d_in[5];
    float* outp = (float*)d_out;

    const int B = in_sizes[0] / 1024;   // 8192 rows
    const int grid = B / 4;             // 4 rows (waves) per 256-thread block
    qasa_kernel<<<grid, 256, 0, stream>>>(x, W_in, b_in, qw, W_out, b_out, outp);
}

// Round 7
// 129.726 us; speedup vs baseline: 1.0052x; 1.0052x over previous
//
#include <hip/hip_runtime.h>
#include <math.h>

// QASA layer: out = circuit(x @ W_in.T + b_in, q_weights) @ W_out.T + b_out
// 8 qubits -> 256 complex amps. One row per wave (8192 waves).
// State idx = lane*4 + r: idx bits [7:2] = lane bits [5:0], [1:0] = reg.
// Wire i acts on idx bit 7-i: wires 0..5 -> lane bits 5..0, wires 6,7 -> regs.
// Registers PACKED as v2 (VOP3P packed fp32): pack A = regs(0,1), B = regs(2,3).
// Cross-lane ops (per 32-bit component, all VALU-pipe, verified round 6):
//   masks 1,2,8 -> DPP; mask 4 -> row_ror:4/12 + cndmask;
//   masks 16,32 -> permlane16/32_swap, partner = r0+r1-v (direction-immune).

typedef float v2 __attribute__((ext_vector_type(2)));

__device__ __forceinline__ int f2i(float v) { return __float_as_int(v); }
__device__ __forceinline__ float i2f(int v) { return __int_as_float(v); }
__device__ __forceinline__ v2 mk2(float a, float b) { v2 r; r.x = a; r.y = b; return r; }
__device__ __forceinline__ v2 splat2(float f) { return mk2(f, f); }
__device__ __forceinline__ v2 swap2(v2 v) { return __builtin_shufflevector(v, v, 1, 0); }

#if __has_builtin(__builtin_elementwise_fma)
__device__ __forceinline__ v2 fma2(v2 a, v2 b, v2 c) { return __builtin_elementwise_fma(a, b, c); }
#else
__device__ __forceinline__ v2 fma2(v2 a, v2 b, v2 c) { return mk2(fmaf(a.x, b.x, c.x), fmaf(a.y, b.y, c.y)); }
#endif

// plain DPP move (all lanes written)
template <int CTRL>
__device__ __forceinline__ float dppf(float v) {
    return i2f(__builtin_amdgcn_update_dpp(0, f2i(v), CTRL, 0xF, 0xF, true));
}
// masked DPP: lanes outside ROW/BANK masks keep `old`
template <int CTRL, int ROW, int BANK>
__device__ __forceinline__ float dppm(float old_, float src) {
    return i2f(__builtin_amdgcn_update_dpp(f2i(old_), f2i(src), CTRL, ROW, BANK, false));
}

#if __has_builtin(__builtin_amdgcn_permlane32_swap) && __has_builtin(__builtin_amdgcn_permlane16_swap)
#define HAVE_PLSWAP 1
#endif

// partner<M>(v): value of v in lane (lane ^ M)  [verified round 6]
template <int MASK>
__device__ __forceinline__ float partner(float v, int lane) {
    if constexpr (MASK == 1)      return dppf<0xB1>(v);
    else if constexpr (MASK == 2) return dppf<0x4E>(v);
    else if constexpr (MASK == 8) return dppf<0x128>(v);
    else if constexpr (MASK == 4) {
        float a = dppf<0x124>(v);   // row_ror:4  : right when bit2==1
        float b = dppf<0x12C>(v);   // row_ror:12 : right when bit2==0
        return (lane & 4) ? a : b;
    }
#ifdef HAVE_PLSWAP
    else if constexpr (MASK == 16) {
        auto r = __builtin_amdgcn_permlane16_swap(f2i(v), f2i(v), false, false);
        return (i2f(r[0]) + i2f(r[1])) - v;
    } else {
        auto r = __builtin_amdgcn_permlane32_swap(f2i(v), f2i(v), false, false);
        return (i2f(r[0]) + i2f(r[1])) - v;
    }
#else
    else if constexpr (MASK == 16)
        return i2f(__builtin_amdgcn_ds_swizzle(f2i(v), 0x401F));
    else
        return __shfl_xor(v, 32, 64);
#endif
}

template <int MASK>
__device__ __forceinline__ v2 partner2(v2 v, int lane) {
    return mk2(partner<MASK>(v.x, lane), partner<MASK>(v.y, lane));
}

template <int L>
__device__ __forceinline__ float rdlane(float v) {
    return i2f(__builtin_amdgcn_readlane(f2i(v), L));
}

// RX(th1) then RZ(th2) on wire W, packed state
template <int W>
__device__ __forceinline__ void rotp(v2& reA, v2& reB, v2& imA, v2& imB,
                                     float c1, float s1, float c2, float s2,
                                     int lane) {
    const v2 c1v = splat2(c1), s1v = splat2(s1), ns1v = splat2(-s1);
    const v2 c2v = splat2(c2);
    if constexpr (W <= 5) {
        constexpr int MASK = 1 << (5 - W);
        v2 prA = partner2<MASK>(reA, lane), prB = partner2<MASK>(reB, lane);
        v2 piA = partner2<MASK>(imA, lane), piB = partner2<MASK>(imB, lane);
        // RX: re' = c1*re + s1*pim ; im' = c1*im - s1*pre
        reA = fma2(s1v, piA, c1v * reA);  reB = fma2(s1v, piB, c1v * reB);
        imA = fma2(ns1v, prA, c1v * imA); imB = fma2(ns1v, prB, c1v * imB);
        // RZ: ss = bit ? s2 : -s2 ; re' = c2*re - ss*im ; im' = c2*im + ss*re
        float ss = (lane & MASK) ? s2 : -s2;
        v2 ssv = splat2(ss);
        v2 t2A = ssv * imA, t2B = ssv * imB;
        v2 t1A = ssv * reA, t1B = ssv * reB;
        reA = fma2(c2v, reA, -t2A); reB = fma2(c2v, reB, -t2B);
        imA = fma2(c2v, imA, t1A);  imB = fma2(c2v, imB, t1B);
    } else if constexpr (W == 6) {
        // pairs (0,2),(1,3): pack A <-> pack B, no exchange
        v2 nreA = fma2(s1v, imB, c1v * reA);
        v2 nimA = fma2(ns1v, reB, c1v * imA);
        v2 nreB = fma2(s1v, imA, c1v * reB);
        v2 nimB = fma2(ns1v, reA, c1v * imB);
        // RZ: pack A (regs 0,1, bit1=0) ss=-s2 ; pack B ss=+s2
        v2 s2v = splat2(s2), ns2v = splat2(-s2);
        reA = fma2(s2v, nimA, c2v * nreA);
        imA = fma2(ns2v, nreA, c2v * nimA);
        reB = fma2(ns2v, nimB, c2v * nreB);
        imB = fma2(s2v, nreB, c2v * nimB);
    } else {
        // W == 7: pairs (0,1) within pack -> component swap (op_sel-foldable)
        v2 sIA = swap2(imA), sIB = swap2(imB);
        v2 sRA = swap2(reA), sRB = swap2(reB);
        reA = fma2(s1v, sIA, c1v * reA);  reB = fma2(s1v, sIB, c1v * reB);
        imA = fma2(ns1v, sRA, c1v * imA); imB = fma2(ns1v, sRB, c1v * imB);
        // RZ: comp0 (r even) ss=-s2, comp1 ss=+s2
        v2 ssv = mk2(-s2, s2);
        v2 t2A = ssv * imA, t2B = ssv * imB;
        v2 t1A = ssv * reA, t1B = ssv * reB;
        reA = fma2(c2v, reA, -t2A); reB = fma2(c2v, reB, -t2B);
        imA = fma2(c2v, imA, t1A);  imB = fma2(c2v, imB, t1B);
    }
}

// ---- CNOTs (control wire i -> target wire i+1) on packed state ----
// ctrl lane bit5, tgt mask16
__device__ __forceinline__ void cnot_01(v2& reA, v2& reB, v2& imA, v2& imB, int lane) {
    const bool c = lane & 32;
    v2 pa = partner2<16>(reA, lane); reA = c ? pa : reA;
    v2 pb = partner2<16>(reB, lane); reB = c ? pb : reB;
    v2 qa = partner2<16>(imA, lane); imA = c ? qa : imA;
    v2 qb = partner2<16>(imB, lane); imB = c ? qb : imB;
}
// ctrl lane bit4 (rows 1,3), tgt mask8: masked row_ror:8
__device__ __forceinline__ float cm12(float v) { return dppm<0x128, 0xA, 0xF>(v, v); }
__device__ __forceinline__ void cnot_12(v2& reA, v2& reB, v2& imA, v2& imB) {
    reA.x = cm12(reA.x); reA.y = cm12(reA.y); reB.x = cm12(reB.x); reB.y = cm12(reB.y);
    imA.x = cm12(imA.x); imA.y = cm12(imA.y); imB.x = cm12(imB.x); imB.y = cm12(imB.y);
}
// ctrl lane bit3 (banks 2,3), tgt mask4: bank2 ror:12, bank3 ror:4  [verified r6]
__device__ __forceinline__ float cm23(float v) {
    float t = dppm<0x12C, 0xF, 0x4>(v, v);
    return dppm<0x124, 0xF, 0x8>(t, v);
}
__device__ __forceinline__ void cnot_23(v2& reA, v2& reB, v2& imA, v2& imB) {
    reA.x = cm23(reA.x); reA.y = cm23(reA.y); reB.x = cm23(reB.x); reB.y = cm23(reB.y);
    imA.x = cm23(imA.x); imA.y = cm23(imA.y); imB.x = cm23(imB.x); imB.y = cm23(imB.y);
}
// ctrl lane bit2 (banks 1,3), tgt mask2: masked quad_perm [2,3,0,1]
__device__ __forceinline__ float cm34(float v) { return dppm<0x4E, 0xF, 0xA>(v, v); }
__device__ __forceinline__ void cnot_34(v2& reA, v2& reB, v2& imA, v2& imB) {
    reA.x = cm34(reA.x); reA.y = cm34(reA.y); reB.x = cm34(reB.x); reB.y = cm34(reB.y);
    imA.x = cm34(imA.x); imA.y = cm34(imA.y); imB.x = cm34(imB.x); imB.y = cm34(imB.y);
}
// ctrl lane bit1, tgt mask1: quad_perm [0,1,3,2]
__device__ __forceinline__ float cm45(float v) { return dppf<0xB4>(v); }
__device__ __forceinline__ void cnot_45(v2& reA, v2& reB, v2& imA, v2& imB) {
    reA.x = cm45(reA.x); reA.y = cm45(reA.y); reB.x = cm45(reB.x); reB.y = cm45(reB.y);
    imA.x = cm45(imA.x); imA.y = cm45(imA.y); imB.x = cm45(imB.x); imB.y = cm45(imB.y);
}
// ctrl lane bit0, tgt reg bit1: swap pack A <-> pack B where ctrl
__device__ __forceinline__ void cnot_56(v2& reA, v2& reB, v2& imA, v2& imB, int lane) {
    const bool c = lane & 1;
    v2 a = reA, b = reB;
    reA = c ? b : a; reB = c ? a : b;
    v2 ai = imA, bi = imB;
    imA = c ? bi : ai; imB = c ? ai : bi;
}
// ctrl reg bit1, tgt reg bit0: swap comps of pack B
__device__ __forceinline__ void cnot_67(v2& reB, v2& imB) {
    reB = swap2(reB); imB = swap2(imB);
}

__global__ void __launch_bounds__(256, 8) qasa_kernel(
    const float* __restrict__ x, const float* __restrict__ W_in,
    const float* __restrict__ b_in, const float* __restrict__ qw,
    const float* __restrict__ W_out, const float* __restrict__ b_out,
    float* __restrict__ out)
{
    const int tid = threadIdx.x;
    const int lane = tid & 63;
    const size_t row = (size_t)blockIdx.x * 4 + (tid >> 6);

    // per-wave layer trig, lane-indexed (qw has exactly 64 entries)
    float vc, vs;
    __sincosf(0.5f * qw[lane], &vs, &vc);

    // ---- phase 1: angles = x[row] @ W_in.T + b_in (packed dot) ----
    v2 acc[8];
#pragma unroll
    for (int q = 0; q < 8; ++q) acc[q] = splat2(0.f);
    {
        const float4* xr = (const float4*)(x + row * 1024);
        const float4* w4 = (const float4*)W_in;
#pragma unroll
        for (int k = 0; k < 4; ++k) {
            float4 xv = xr[lane + 64 * k];
            v2 xlo = mk2(xv.x, xv.y), xhi = mk2(xv.z, xv.w);
#pragma unroll
            for (int q = 0; q < 8; ++q) {
                float4 wv = w4[q * 256 + lane + 64 * k];
                acc[q] = fma2(mk2(wv.x, wv.y), xlo, acc[q]);
                acc[q] = fma2(mk2(wv.z, wv.w), xhi, acc[q]);
            }
        }
    }
    float accs[8];
#pragma unroll
    for (int q = 0; q < 8; ++q) {
        float a = acc[q].x + acc[q].y;
        a += dppf<0xB1>(a);
        a += dppf<0x4E>(a);
        a += dppf<0x128>(a);
        accs[q] = a;
    }
    // transpose: lane picks accs[j], j = b0 | b1<<1 | b3<<2
    const int b0 = lane & 1, b1 = (lane >> 1) & 1, b3 = (lane >> 3) & 1;
    float t01 = b0 ? accs[1] : accs[0];
    float t23 = b0 ? accs[3] : accs[2];
    float t45 = b0 ? accs[5] : accs[4];
    float t67 = b0 ? accs[7] : accs[6];
    float ta = b1 ? t23 : t01;
    float tb = b1 ? t67 : t45;
    float A = b3 ? tb : ta;
    A += partner<4>(A, lane);
    A += partner<16>(A, lane);
    A += partner<32>(A, lane);
    A += b_in[b0 | (b1 << 1) | (b3 << 2)];
    float ec, es;
    __sincosf(0.5f * A, &es, &ec);  // lane L_q holds trig of angle q

    // ---- phase 2: circuit (packed state) ----
    v2 reA = mk2((lane == 0) ? 1.f : 0.f, 0.f);
    v2 reB = splat2(0.f), imA = splat2(0.f), imB = splat2(0.f);

    // embedding: RX(ang[q]);RZ(ang[q]) on wire q, trig in lane
    // L_q = (q&1) | ((q>>1)&1)<<1 | ((q>>2)&1)<<3
#define EMB(W_) { constexpr int L_ = ((W_) & 1) | ((((W_) >> 1) & 1) << 1) | ((((W_) >> 2) & 1) << 3); \
                  float c_ = rdlane<L_>(ec), s_ = rdlane<L_>(es); \
                  rotp<W_>(reA, reB, imA, imB, c_, s_, c_, s_, lane); }
    EMB(0) EMB(1) EMB(2) EMB(3) EMB(4) EMB(5) EMB(6) EMB(7)
#undef EMB

    // layers: qw[l][0][i] -> lane 16l+i (RX), qw[l][1][i] -> lane 16l+8+i (RZ)
#define LGATE(Lx, I_) rotp<I_>(reA, reB, imA, imB, \
        rdlane<16 * (Lx) + (I_)>(vc), rdlane<16 * (Lx) + (I_)>(vs), \
        rdlane<16 * (Lx) + 8 + (I_)>(vc), rdlane<16 * (Lx) + 8 + (I_)>(vs), lane);
#define LAYER(Lx) \
    LGATE(Lx, 0) LGATE(Lx, 1) LGATE(Lx, 2) LGATE(Lx, 3) \
    LGATE(Lx, 4) LGATE(Lx, 5) LGATE(Lx, 6) LGATE(Lx, 7) \
    cnot_01(reA, reB, imA, imB, lane); \
    cnot_12(reA, reB, imA, imB); \
    cnot_23(reA, reB, imA, imB); \
    cnot_34(reA, reB, imA, imB); \
    cnot_45(reA, reB, imA, imB); \
    cnot_56(reA, reB, imA, imB, lane); \
    cnot_67(reB, imB);
    LAYER(0) LAYER(1) LAYER(2) LAYER(3)
#undef LAYER
#undef LGATE

    // ---- phase 3: expvals ----
    v2 pA = fma2(reA, reA, imA * imA);
    v2 pB = fma2(reB, reB, imB * imB);
    float p0 = pA.x, p1 = pA.y, p2 = pB.x, p3 = pB.y;
    float psum = (p0 + p1) + (p2 + p3);
    float s6 = (p0 + p1) - (p2 + p3);   // wire6: reg bit1
    float s7 = (p0 + p2) - (p1 + p3);   // wire7: reg bit0

    // Walsh-Hadamard butterfly on psum: lane 2^b ends with <Z> for lane-bit b
    float v = psum;
    { float u = dppf<0xB1>(v);        v = (lane & 1)  ? (u - v) : (v + u); }
    { float u = dppf<0x4E>(v);        v = (lane & 2)  ? (u - v) : (v + u); }
    { float u = dppf<0x128>(v);       v = (lane & 8)  ? (u - v) : (v + u); }
    { float u = partner<4>(v, lane);  v = (lane & 4)  ? (u - v) : (v + u); }
    { float u = partner<16>(v, lane); v = (lane & 16) ? (u - v) : (v + u); }
    { float u = partner<32>(v, lane); v = (lane & 32) ? (u - v) : (v + u); }
    const float EV0 = rdlane<32>(v), EV1 = rdlane<16>(v), EV2 = rdlane<8>(v);
    const float EV3 = rdlane<4>(v),  EV4 = rdlane<2>(v),  EV5 = rdlane<1>(v);

    // s6/s7: partial DPP sums, interleave by bit0, finish with shared butterfly
    s6 += dppf<0xB1>(s6); s6 += dppf<0x4E>(s6); s6 += dppf<0x128>(s6);
    s7 += dppf<0xB1>(s7); s7 += dppf<0x4E>(s7); s7 += dppf<0x128>(s7);
    float w = (lane & 1) ? s7 : s6;
    w += partner<4>(w, lane);
    w += partner<16>(w, lane);
    w += partner<32>(w, lane);
    const float EV6 = rdlane<0>(w), EV7 = rdlane<1>(w);

    // ---- phase 4: out[row] = ev @ W_out.T + b_out (packed epilogue) ----
    const v2 ev01 = mk2(EV0, EV1), ev23 = mk2(EV2, EV3);
    const v2 ev45 = mk2(EV4, EV5), ev67 = mk2(EV6, EV7);
    const float4* wo = (const float4*)W_out;
    const float4* bo = (const float4*)b_out;
    float4* orow = (float4*)(out + row * 1024);
#pragma unroll
    for (int jj = 0; jj < 4; ++jj) {
        const int c4 = lane + 64 * jj;      // float4-col index; col0 = 4*c4
        float4 bias = bo[c4];
        float res[4];
#pragma unroll
        for (int c = 0; c < 4; ++c) {
            float4 wa = wo[2 * (4 * c4 + c)];
            float4 wb = wo[2 * (4 * c4 + c) + 1];
            v2 r2 = mk2(wa.x, wa.y) * ev01;
            r2 = fma2(mk2(wa.z, wa.w), ev23, r2);
            r2 = fma2(mk2(wb.x, wb.y), ev45, r2);
            r2 = fma2(mk2(wb.z, wb.w), ev67, r2);
            res[c] = r2.x + r2.y;
        }
        float4 o;
        o.x = bias.x + res[0]; o.y = bias.y + res[1];
        o.z = bias.z + res[2]; o.w = bias.w + res[3];
        orow[c4] = o;
    }
}

extern "C" void kernel_launch(void* const* d_in, const int* in_sizes, int n_in,
                              void* d_out, int out_size, void* d_ws, size_t ws_size,
                              hipStream_t stream) {
    const float* x     = (const float*)d_in[0];
    const float* W_in  = (const float*)d_in[1];
    const float* b_in  = (const float*)d_in[2];
    const float* qw    = (const float*)d_in[3];
    const float* W_out = (const float*)d_in[4];
    const float* b_out = (const float*)d_in[5];
    float* outp = (float*)d_out;

    const int B = in_sizes[0] / 1024;   // 8192 rows
    const int grid = B / 4;             // 4 rows (waves) per 256-thread block
    qasa_kernel<<<grid, 256, 0, stream>>>(x, W_in, b_in, qw, W_out, b_out, outp);
}

// Round 8
// 129.249 us; speedup vs baseline: 1.0089x; 1.0037x over previous
//
#include <hip/hip_runtime.h>
#include <math.h>

// QASA layer: out = circuit(x @ W_in.T + b_in, q_weights) @ W_out.T + b_out
// 8 qubits -> 256 complex amps. One row per wave (8192 waves).
// State idx = lane*4 + r: idx bits [7:2] = lane bits [5:0], [1:0] = reg.
// Wire i acts on idx bit 7-i: wires 0..5 -> lane bits 5..0, wires 6,7 -> regs.
// Registers PACKED as v2 (VOP3P packed fp32): pack A = regs(0,1), B = regs(2,3).
// Cross-lane ops (per 32-bit component, all VALU-pipe, verified round 6):
//   masks 1,2,8 -> DPP; mask 4 -> row_ror:4/12 + cndmask;
//   masks 16,32 -> permlane16/32_swap, partner = r0+r1-v (direction-immune).
// ROUND 8: layer loop NOT unrolled (I-cache residency test) — trig readlane
// index is runtime (base = 16*l), everything else identical to round 7.

typedef float v2 __attribute__((ext_vector_type(2)));

__device__ __forceinline__ int f2i(float v) { return __float_as_int(v); }
__device__ __forceinline__ float i2f(int v) { return __int_as_float(v); }
__device__ __forceinline__ v2 mk2(float a, float b) { v2 r; r.x = a; r.y = b; return r; }
__device__ __forceinline__ v2 splat2(float f) { return mk2(f, f); }
__device__ __forceinline__ v2 swap2(v2 v) { return __builtin_shufflevector(v, v, 1, 0); }

#if __has_builtin(__builtin_elementwise_fma)
__device__ __forceinline__ v2 fma2(v2 a, v2 b, v2 c) { return __builtin_elementwise_fma(a, b, c); }
#else
__device__ __forceinline__ v2 fma2(v2 a, v2 b, v2 c) { return mk2(fmaf(a.x, b.x, c.x), fmaf(a.y, b.y, c.y)); }
#endif

// plain DPP move (all lanes written)
template <int CTRL>
__device__ __forceinline__ float dppf(float v) {
    return i2f(__builtin_amdgcn_update_dpp(0, f2i(v), CTRL, 0xF, 0xF, true));
}
// masked DPP: lanes outside ROW/BANK masks keep `old`
template <int CTRL, int ROW, int BANK>
__device__ __forceinline__ float dppm(float old_, float src) {
    return i2f(__builtin_amdgcn_update_dpp(f2i(old_), f2i(src), CTRL, ROW, BANK, false));
}

#if __has_builtin(__builtin_amdgcn_permlane32_swap) && __has_builtin(__builtin_amdgcn_permlane16_swap)
#define HAVE_PLSWAP 1
#endif

// partner<M>(v): value of v in lane (lane ^ M)  [verified round 6]
template <int MASK>
__device__ __forceinline__ float partner(float v, int lane) {
    if constexpr (MASK == 1)      return dppf<0xB1>(v);
    else if constexpr (MASK == 2) return dppf<0x4E>(v);
    else if constexpr (MASK == 8) return dppf<0x128>(v);
    else if constexpr (MASK == 4) {
        float a = dppf<0x124>(v);   // row_ror:4  : right when bit2==1
        float b = dppf<0x12C>(v);   // row_ror:12 : right when bit2==0
        return (lane & 4) ? a : b;
    }
#ifdef HAVE_PLSWAP
    else if constexpr (MASK == 16) {
        auto r = __builtin_amdgcn_permlane16_swap(f2i(v), f2i(v), false, false);
        return (i2f(r[0]) + i2f(r[1])) - v;
    } else {
        auto r = __builtin_amdgcn_permlane32_swap(f2i(v), f2i(v), false, false);
        return (i2f(r[0]) + i2f(r[1])) - v;
    }
#else
    else if constexpr (MASK == 16)
        return i2f(__builtin_amdgcn_ds_swizzle(f2i(v), 0x401F));
    else
        return __shfl_xor(v, 32, 64);
#endif
}

template <int MASK>
__device__ __forceinline__ v2 partner2(v2 v, int lane) {
    return mk2(partner<MASK>(v.x, lane), partner<MASK>(v.y, lane));
}

template <int L>
__device__ __forceinline__ float rdlane(float v) {
    return i2f(__builtin_amdgcn_readlane(f2i(v), L));
}
__device__ __forceinline__ float rdlaned(float v, int l) {
    return i2f(__builtin_amdgcn_readlane(f2i(v), l));
}

// RX(th1) then RZ(th2) on wire W, packed state
template <int W>
__device__ __forceinline__ void rotp(v2& reA, v2& reB, v2& imA, v2& imB,
                                     float c1, float s1, float c2, float s2,
                                     int lane) {
    const v2 c1v = splat2(c1), s1v = splat2(s1), ns1v = splat2(-s1);
    const v2 c2v = splat2(c2);
    if constexpr (W <= 5) {
        constexpr int MASK = 1 << (5 - W);
        v2 prA = partner2<MASK>(reA, lane), prB = partner2<MASK>(reB, lane);
        v2 piA = partner2<MASK>(imA, lane), piB = partner2<MASK>(imB, lane);
        // RX: re' = c1*re + s1*pim ; im' = c1*im - s1*pre
        reA = fma2(s1v, piA, c1v * reA);  reB = fma2(s1v, piB, c1v * reB);
        imA = fma2(ns1v, prA, c1v * imA); imB = fma2(ns1v, prB, c1v * imB);
        // RZ: ss = bit ? s2 : -s2 ; re' = c2*re - ss*im ; im' = c2*im + ss*re
        float ss = (lane & MASK) ? s2 : -s2;
        v2 ssv = splat2(ss);
        v2 t2A = ssv * imA, t2B = ssv * imB;
        v2 t1A = ssv * reA, t1B = ssv * reB;
        reA = fma2(c2v, reA, -t2A); reB = fma2(c2v, reB, -t2B);
        imA = fma2(c2v, imA, t1A);  imB = fma2(c2v, imB, t1B);
    } else if constexpr (W == 6) {
        // pairs (0,2),(1,3): pack A <-> pack B, no exchange
        v2 nreA = fma2(s1v, imB, c1v * reA);
        v2 nimA = fma2(ns1v, reB, c1v * imA);
        v2 nreB = fma2(s1v, imA, c1v * reB);
        v2 nimB = fma2(ns1v, reA, c1v * imB);
        // RZ: pack A (regs 0,1, bit1=0) ss=-s2 ; pack B ss=+s2
        v2 s2v = splat2(s2), ns2v = splat2(-s2);
        reA = fma2(s2v, nimA, c2v * nreA);
        imA = fma2(ns2v, nreA, c2v * nimA);
        reB = fma2(ns2v, nimB, c2v * nreB);
        imB = fma2(s2v, nreB, c2v * nimB);
    } else {
        // W == 7: pairs (0,1) within pack -> component swap (op_sel-foldable)
        v2 sIA = swap2(imA), sIB = swap2(imB);
        v2 sRA = swap2(reA), sRB = swap2(reB);
        reA = fma2(s1v, sIA, c1v * reA);  reB = fma2(s1v, sIB, c1v * reB);
        imA = fma2(ns1v, sRA, c1v * imA); imB = fma2(ns1v, sRB, c1v * imB);
        // RZ: comp0 (r even) ss=-s2, comp1 ss=+s2
        v2 ssv = mk2(-s2, s2);
        v2 t2A = ssv * imA, t2B = ssv * imB;
        v2 t1A = ssv * reA, t1B = ssv * reB;
        reA = fma2(c2v, reA, -t2A); reB = fma2(c2v, reB, -t2B);
        imA = fma2(c2v, imA, t1A);  imB = fma2(c2v, imB, t1B);
    }
}

// ---- CNOTs (control wire i -> target wire i+1) on packed state ----
// ctrl lane bit5, tgt mask16
__device__ __forceinline__ void cnot_01(v2& reA, v2& reB, v2& imA, v2& imB, int lane) {
    const bool c = lane & 32;
    v2 pa = partner2<16>(reA, lane); reA = c ? pa : reA;
    v2 pb = partner2<16>(reB, lane); reB = c ? pb : reB;
    v2 qa = partner2<16>(imA, lane); imA = c ? qa : imA;
    v2 qb = partner2<16>(imB, lane); imB = c ? qb : imB;
}
// ctrl lane bit4 (rows 1,3), tgt mask8: masked row_ror:8
__device__ __forceinline__ float cm12(float v) { return dppm<0x128, 0xA, 0xF>(v, v); }
__device__ __forceinline__ void cnot_12(v2& reA, v2& reB, v2& imA, v2& imB) {
    reA.x = cm12(reA.x); reA.y = cm12(reA.y); reB.x = cm12(reB.x); reB.y = cm12(reB.y);
    imA.x = cm12(imA.x); imA.y = cm12(imA.y); imB.x = cm12(imB.x); imB.y = cm12(imB.y);
}
// ctrl lane bit3 (banks 2,3), tgt mask4: bank2 ror:12, bank3 ror:4  [verified r6]
__device__ __forceinline__ float cm23(float v) {
    float t = dppm<0x12C, 0xF, 0x4>(v, v);
    return dppm<0x124, 0xF, 0x8>(t, v);
}
__device__ __forceinline__ void cnot_23(v2& reA, v2& reB, v2& imA, v2& imB) {
    reA.x = cm23(reA.x); reA.y = cm23(reA.y); reB.x = cm23(reB.x); reB.y = cm23(reB.y);
    imA.x = cm23(imA.x); imA.y = cm23(imA.y); imB.x = cm23(imB.x); imB.y = cm23(imB.y);
}
// ctrl lane bit2 (banks 1,3), tgt mask2: masked quad_perm [2,3,0,1]
__device__ __forceinline__ float cm34(float v) { return dppm<0x4E, 0xF, 0xA>(v, v); }
__device__ __forceinline__ void cnot_34(v2& reA, v2& reB, v2& imA, v2& imB) {
    reA.x = cm34(reA.x); reA.y = cm34(reA.y); reB.x = cm34(reB.x); reB.y = cm34(reB.y);
    imA.x = cm34(imA.x); imA.y = cm34(imA.y); imB.x = cm34(imB.x); imB.y = cm34(imB.y);
}
// ctrl lane bit1, tgt mask1: quad_perm [0,1,3,2]
__device__ __forceinline__ float cm45(float v) { return dppf<0xB4>(v); }
__device__ __forceinline__ void cnot_45(v2& reA, v2& reB, v2& imA, v2& imB) {
    reA.x = cm45(reA.x); reA.y = cm45(reA.y); reB.x = cm45(reB.x); reB.y = cm45(reB.y);
    imA.x = cm45(imA.x); imA.y = cm45(imA.y); imB.x = cm45(imB.x); imB.y = cm45(imB.y);
}
// ctrl lane bit0, tgt reg bit1: swap pack A <-> pack B where ctrl
__device__ __forceinline__ void cnot_56(v2& reA, v2& reB, v2& imA, v2& imB, int lane) {
    const bool c = lane & 1;
    v2 a = reA, b = reB;
    reA = c ? b : a; reB = c ? a : b;
    v2 ai = imA, bi = imB;
    imA = c ? bi : ai; imB = c ? ai : bi;
}
// ctrl reg bit1, tgt reg bit0: swap comps of pack B
__device__ __forceinline__ void cnot_67(v2& reB, v2& imB) {
    reB = swap2(reB); imB = swap2(imB);
}

__global__ void __launch_bounds__(256, 8) qasa_kernel(
    const float* __restrict__ x, const float* __restrict__ W_in,
    const float* __restrict__ b_in, const float* __restrict__ qw,
    const float* __restrict__ W_out, const float* __restrict__ b_out,
    float* __restrict__ out)
{
    const int tid = threadIdx.x;
    const int lane = tid & 63;
    const size_t row = (size_t)blockIdx.x * 4 + (tid >> 6);

    // per-wave layer trig, lane-indexed (qw has exactly 64 entries)
    float vc, vs;
    __sincosf(0.5f * qw[lane], &vs, &vc);

    // ---- phase 1: angles = x[row] @ W_in.T + b_in (packed dot) ----
    v2 acc[8];
#pragma unroll
    for (int q = 0; q < 8; ++q) acc[q] = splat2(0.f);
    {
        const float4* xr = (const float4*)(x + row * 1024);
        const float4* w4 = (const float4*)W_in;
#pragma unroll
        for (int k = 0; k < 4; ++k) {
            float4 xv = xr[lane + 64 * k];
            v2 xlo = mk2(xv.x, xv.y), xhi = mk2(xv.z, xv.w);
#pragma unroll
            for (int q = 0; q < 8; ++q) {
                float4 wv = w4[q * 256 + lane + 64 * k];
                acc[q] = fma2(mk2(wv.x, wv.y), xlo, acc[q]);
                acc[q] = fma2(mk2(wv.z, wv.w), xhi, acc[q]);
            }
        }
    }
    float accs[8];
#pragma unroll
    for (int q = 0; q < 8; ++q) {
        float a = acc[q].x + acc[q].y;
        a += dppf<0xB1>(a);
        a += dppf<0x4E>(a);
        a += dppf<0x128>(a);
        accs[q] = a;
    }
    // transpose: lane picks accs[j], j = b0 | b1<<1 | b3<<2
    const int b0 = lane & 1, b1 = (lane >> 1) & 1, b3 = (lane >> 3) & 1;
    float t01 = b0 ? accs[1] : accs[0];
    float t23 = b0 ? accs[3] : accs[2];
    float t45 = b0 ? accs[5] : accs[4];
    float t67 = b0 ? accs[7] : accs[6];
    float ta = b1 ? t23 : t01;
    float tb = b1 ? t67 : t45;
    float A = b3 ? tb : ta;
    A += partner<4>(A, lane);
    A += partner<16>(A, lane);
    A += partner<32>(A, lane);
    A += b_in[b0 | (b1 << 1) | (b3 << 2)];
    float ec, es;
    __sincosf(0.5f * A, &es, &ec);  // lane L_q holds trig of angle q

    // ---- phase 2: circuit (packed state) ----
    v2 reA = mk2((lane == 0) ? 1.f : 0.f, 0.f);
    v2 reB = splat2(0.f), imA = splat2(0.f), imB = splat2(0.f);

    // embedding: RX(ang[q]);RZ(ang[q]) on wire q, trig in lane
    // L_q = (q&1) | ((q>>1)&1)<<1 | ((q>>2)&1)<<3
#define EMB(W_) { constexpr int L_ = ((W_) & 1) | ((((W_) >> 1) & 1) << 1) | ((((W_) >> 2) & 1) << 3); \
                  float c_ = rdlane<L_>(ec), s_ = rdlane<L_>(es); \
                  rotp<W_>(reA, reB, imA, imB, c_, s_, c_, s_, lane); }
    EMB(0) EMB(1) EMB(2) EMB(3) EMB(4) EMB(5) EMB(6) EMB(7)
#undef EMB

    // layers in a REAL loop (I$-resident body); trig lanes are runtime:
    // qw[l][0][i] -> lane 16l+i (RX), qw[l][1][i] -> lane 16l+8+i (RZ)
#define LGATE(I_) rotp<I_>(reA, reB, imA, imB, \
        rdlaned(vc, base + (I_)), rdlaned(vs, base + (I_)), \
        rdlaned(vc, base + 8 + (I_)), rdlaned(vs, base + 8 + (I_)), lane);
#pragma unroll 1
    for (int l = 0; l < 4; ++l) {
        const int base = l << 4;
        LGATE(0) LGATE(1) LGATE(2) LGATE(3)
        LGATE(4) LGATE(5) LGATE(6) LGATE(7)
        cnot_01(reA, reB, imA, imB, lane);
        cnot_12(reA, reB, imA, imB);
        cnot_23(reA, reB, imA, imB);
        cnot_34(reA, reB, imA, imB);
        cnot_45(reA, reB, imA, imB);
        cnot_56(reA, reB, imA, imB, lane);
        cnot_67(reB, imB);
    }
#undef LGATE

    // ---- phase 3: expvals ----
    v2 pA = fma2(reA, reA, imA * imA);
    v2 pB = fma2(reB, reB, imB * imB);
    float p0 = pA.x, p1 = pA.y, p2 = pB.x, p3 = pB.y;
    float psum = (p0 + p1) + (p2 + p3);
    float s6 = (p0 + p1) - (p2 + p3);   // wire6: reg bit1
    float s7 = (p0 + p2) - (p1 + p3);   // wire7: reg bit0

    // Walsh-Hadamard butterfly on psum: lane 2^b ends with <Z> for lane-bit b
    float v = psum;
    { float u = dppf<0xB1>(v);        v = (lane & 1)  ? (u - v) : (v + u); }
    { float u = dppf<0x4E>(v);        v = (lane & 2)  ? (u - v) : (v + u); }
    { float u = dppf<0x128>(v);       v = (lane & 8)  ? (u - v) : (v + u); }
    { float u = partner<4>(v, lane);  v = (lane & 4)  ? (u - v) : (v + u); }
    { float u = partner<16>(v, lane); v = (lane & 16) ? (u - v) : (v + u); }
    { float u = partner<32>(v, lane); v = (lane & 32) ? (u - v) : (v + u); }
    const float EV0 = rdlane<32>(v), EV1 = rdlane<16>(v), EV2 = rdlane<8>(v);
    const float EV3 = rdlane<4>(v),  EV4 = rdlane<2>(v),  EV5 = rdlane<1>(v);

    // s6/s7: partial DPP sums, interleave by bit0, finish with shared butterfly
    s6 += dppf<0xB1>(s6); s6 += dppf<0x4E>(s6); s6 += dppf<0x128>(s6);
    s7 += dppf<0xB1>(s7); s7 += dppf<0x4E>(s7); s7 += dppf<0x128>(s7);
    float w = (lane & 1) ? s7 : s6;
    w += partner<4>(w, lane);
    w += partner<16>(w, lane);
    w += partner<32>(w, lane);
    const float EV6 = rdlane<0>(w), EV7 = rdlane<1>(w);

    // ---- phase 4: out[row] = ev @ W_out.T + b_out (packed epilogue) ----
    const v2 ev01 = mk2(EV0, EV1), ev23 = mk2(EV2, EV3);
    const v2 ev45 = mk2(EV4, EV5), ev67 = mk2(EV6, EV7);
    const float4* wo = (const float4*)W_out;
    const float4* bo = (const float4*)b_out;
    float4* orow = (float4*)(out + row * 1024);
#pragma unroll
    for (int jj = 0; jj < 4; ++jj) {
        const int c4 = lane + 64 * jj;      // float4-col index; col0 = 4*c4
        float4 bias = bo[c4];
        float res[4];
#pragma unroll
        for (int c = 0; c < 4; ++c) {
            float4 wa = wo[2 * (4 * c4 + c)];
            float4 wb = wo[2 * (4 * c4 + c) + 1];
            v2 r2 = mk2(wa.x, wa.y) * ev01;
            r2 = fma2(mk2(wa.z, wa.w), ev23, r2);
            r2 = fma2(mk2(wb.x, wb.y), ev45, r2);
            r2 = fma2(mk2(wb.z, wb.w), ev67, r2);
            res[c] = r2.x + r2.y;
        }
        float4 o;
        o.x = bias.x + res[0]; o.y = bias.y + res[1];
        o.z = bias.z + res[2]; o.w = bias.w + res[3];
        orow[c4] = o;
    }
}

extern "C" void kernel_launch(void* const* d_in, const int* in_sizes, int n_in,
                              void* d_out, int out_size, void* d_ws, size_t ws_size,
                              hipStream_t stream) {
    const float* x     = (const float*)d_in[0];
    const float* W_in  = (const float*)d_in[1];
    const float* b_in  = (const float*)d_in[2];
    const float* qw    = (const float*)d_in[3];
    const float* W_out = (const float*)d_in[4];
    const float* b_out = (const float*)d_in[5];
    float* outp = (float*)d_out;

    const int B = in_sizes[0] / 1024;   // 8192 rows
    const int grid = B / 4;             // 4 rows (waves) per 256-thread block
    qasa_kernel<<<grid, 256, 0, stream>>>(x, W_in, b_in, qw, W_out, b_out, outp);
}